// Round 17
// baseline (271.239 us; speedup 1.0000x reference)
//
#include <hip/hip_runtime.h>

#define IN_C 512
#define OUT_C 128
#define NB 128          // dst buckets (dst >> 10)
#define CHUNK 4096      // edges per chunk -> 391 chunks (full CU coverage)

typedef float f32x4 __attribute__((ext_vector_type(4)));
typedef __bf16 bf16x8 __attribute__((ext_vector_type(8)));

static inline int cdiv(int a, int b) { return (a + b - 1) / b; }

__device__ __forceinline__ unsigned short bfbits(__bf16 h) {
  return __builtin_bit_cast(unsigned short, h);
}
__device__ __forceinline__ float bflo(unsigned int u) {
  return __builtin_bit_cast(float, u << 16);
}
__device__ __forceinline__ float bfhi(unsigned int u) {
  return __builtin_bit_cast(float, u & 0xffff0000u);
}

// ---- K1: per-chunk bucket histogram (+ wsplit on extra blocks) ----
__global__ __launch_bounds__(256) void hist_kernel(const int* __restrict__ dst,
                                                   int* __restrict__ table,
                                                   const float* __restrict__ W,
                                                   unsigned short* __restrict__ wfh,
                                                   unsigned short* __restrict__ wfl,
                                                   int nchunks, int E) {
  int c = blockIdx.x;
  int t = threadIdx.x;
  if (c >= nchunks) {
    int i = (c - nchunks) * 256 + t;
    if (i < IN_C * OUT_C) {
      int k = i >> 7;
      int col = i & 127;
      float w = W[i];
      __bf16 hb = (__bf16)w;
      __bf16 lb = (__bf16)(w - (float)hb);
      int ks = k >> 5;
      int lg = (k & 31) >> 3;
      int j = k & 7;
      int cb = col >> 4;
      int lane = lg * 16 + (col & 15);
      size_t idx = ((size_t)(ks * 8 + cb) * 64 + lane) * 8 + j;
      wfh[idx] = bfbits(hb);
      wfl[idx] = bfbits(lb);
    }
    return;
  }
  __shared__ int hcnt[NB];
  if (t < NB) hcnt[t] = 0;
  __syncthreads();
  int base = c * CHUNK;
  int lim = base + CHUNK < E ? base + CHUNK : E;
  for (int e = base + t; e < lim; e += 256) {
    atomicAdd(&hcnt[dst[e] >> 10], 1);
  }
  __syncthreads();
  if (t < NB) table[t * nchunks + c] = hcnt[t];
}

// ---- GEMM tile (device fn): h_raw[row][:] = bf16((x @ W)[row][:]) for one
// 128-row tile. 2-term split-bf16 MFMA, BK=32 double-buffered LDS via
// global_load_lds (16B slots, XOR-swizzled source). Body measured-good; frozen.
__device__ __forceinline__ void gemm_tile(
    const float* __restrict__ x, const unsigned short* __restrict__ wfh,
    const unsigned short* __restrict__ wfl, unsigned short* __restrict__ h,
    int n, int tile) {
  __shared__ float xs[2][4096];  // 2 x 16KB: [128 rows][32 k] swizzled

  const int tid = threadIdx.x;
  const int wv = tid >> 6;
  const int lane = tid & 63;
  const int l15 = lane & 15;
  const int lg = lane >> 4;
  const int wr = wv >> 1;
  const int wc = wv & 1;
  const int row0 = tile * 128;

  const float* gsrc[4];
#pragma unroll
  for (int i = 0; i < 4; i++) {
    int pslot = i * 256 + tid;
    int row = pslot >> 3;
    int q = pslot & 7;
    int s = q ^ (row & 7);
    int grow = row0 + row;
    if (grow > n - 1) grow = n - 1;
    gsrc[i] = x + (size_t)grow * IN_C + s * 4;
  }

  const unsigned short* bph = wfh + ((size_t)(wc * 4) * 64 + lane) * 8;
  const unsigned short* bpl = wfl + ((size_t)(wc * 4) * 64 + lane) * 8;

  f32x4 acc[4][4];
#pragma unroll
  for (int i = 0; i < 4; i++)
#pragma unroll
    for (int j = 0; j < 4; j++) acc[i][j] = (f32x4)0.0f;

#pragma unroll
  for (int i = 0; i < 4; i++) {
    char* lp = (char*)&xs[0][0] + i * 4096 + wv * 1024;
    __builtin_amdgcn_global_load_lds(
        (const __attribute__((address_space(1))) void*)gsrc[i],
        (__attribute__((address_space(3))) void*)lp, 16, 0, 0);
    gsrc[i] += 32;
  }
  __syncthreads();

  int cur = 0;
  for (int ks = 0; ks < 16; ks++) {
    if (ks < 15) {
#pragma unroll
      for (int i = 0; i < 4; i++) {
        char* lp = (char*)&xs[cur ^ 1][0] + i * 4096 + wv * 1024;
        __builtin_amdgcn_global_load_lds(
            (const __attribute__((address_space(1))) void*)gsrc[i],
            (__attribute__((address_space(3))) void*)lp, 16, 0, 0);
        gsrc[i] += 32;
      }
    }
    bf16x8 bh[4], bl[4];
#pragma unroll
    for (int nt = 0; nt < 4; nt++) {
      bh[nt] = __builtin_bit_cast(bf16x8, *(const uint4*)(bph + (size_t)ks * 4096 + nt * 512));
      bl[nt] = __builtin_bit_cast(bf16x8, *(const uint4*)(bpl + (size_t)ks * 4096 + nt * 512));
    }
    const float* bp = &xs[cur][0];
    bf16x8 ah[4];
#pragma unroll
    for (int rt = 0; rt < 4; rt++) {
      int row = wr * 64 + rt * 16 + l15;
      int r7 = row & 7;
      int s0 = (lg * 2) ^ r7;
      int s1 = (lg * 2 + 1) ^ r7;
      float4 f0 = *(const float4*)(bp + row * 32 + s0 * 4);
      float4 f1 = *(const float4*)(bp + row * 32 + s1 * 4);
      float f[8] = {f0.x, f0.y, f0.z, f0.w, f1.x, f1.y, f1.z, f1.w};
      bf16x8 hh;
#pragma unroll
      for (int j = 0; j < 8; j++) hh[j] = (__bf16)f[j];
      ah[rt] = hh;
    }
#pragma unroll
    for (int rt = 0; rt < 4; rt++)
#pragma unroll
      for (int nt = 0; nt < 4; nt++) {
        acc[rt][nt] = __builtin_amdgcn_mfma_f32_16x16x32_bf16(ah[rt], bh[nt], acc[rt][nt], 0, 0, 0);
        acc[rt][nt] = __builtin_amdgcn_mfma_f32_16x16x32_bf16(ah[rt], bl[nt], acc[rt][nt], 0, 0, 0);
      }
    __syncthreads();
    cur ^= 1;
  }

#pragma unroll
  for (int rt = 0; rt < 4; rt++) {
    int rowbase = row0 + wr * 64 + rt * 16 + lg * 4;
#pragma unroll
    for (int r = 0; r < 4; r++) {
      int row = rowbase + r;
      if (row < n) {
#pragma unroll
        for (int nt = 0; nt < 4; nt++) {
          int col = wc * 64 + nt * 16 + l15;
          h[(size_t)row * OUT_C + col] = bfbits((__bf16)acc[rt][nt][r]);
        }
      }
    }
  }
}

// ---- K2: tscan (block 0) + gemm tiles (blocks 1..) ----
__global__ __launch_bounds__(256) void tscan_gemm_kernel(
    int* __restrict__ table, int* __restrict__ bstart,
    const float* __restrict__ x, const unsigned short* __restrict__ wfh,
    const unsigned short* __restrict__ wfl, unsigned short* __restrict__ h,
    int nchunks, int E, int n, int tbase) {
  if (blockIdx.x != 0) {
    gemm_tile(x, wfh, wfl, h, n, tbase + (int)blockIdx.x - 1);
    return;
  }
  __shared__ int sh[256];
  int t = threadIdx.x;
  int total = NB * nchunks;
  int S = (total + 255) / 256;
  int lo = t * S;
  int hi = lo + S; if (hi > total) hi = total;
  int s = 0;
  int i = lo;
  for (; i + 4 <= hi; i += 4)
    s += table[i] + table[i + 1] + table[i + 2] + table[i + 3];
  for (; i < hi; i++) s += table[i];
  sh[t] = s;
  __syncthreads();
  for (int off = 1; off < 256; off <<= 1) {
    int x2 = sh[t];
    if (t >= off) x2 += sh[t - off];
    __syncthreads();
    sh[t] = x2;
    __syncthreads();
  }
  int run = sh[t] - s;
  for (i = lo; i < hi; i++) {
    int v = table[i];
    table[i] = run;
    run += v;
  }
  __syncthreads();
  for (int b = t; b < NB; b += 256) bstart[b] = table[b * nchunks];
  if (t == 0) bstart[NB] = E;
}

// ---- K3: scat2 (blocks < nchunks) + gemm tiles (rest) ----
// scatter edges into bucket-major packed inter[]: (src<<10) | (dst&1023)
__global__ __launch_bounds__(256) void scat2_gemm_kernel(
    const int* __restrict__ src, const int* __restrict__ dst,
    const int* __restrict__ table, int* __restrict__ inter,
    const float* __restrict__ x, const unsigned short* __restrict__ wfh,
    const unsigned short* __restrict__ wfl, unsigned short* __restrict__ h,
    int nchunks, int E, int n, int tbase) {
  if ((int)blockIdx.x >= nchunks) {
    gemm_tile(x, wfh, wfl, h, n, tbase + (int)blockIdx.x - nchunks);
    return;
  }
  __shared__ int cur[NB];
  int t = threadIdx.x;
  int c = blockIdx.x;
  if (t < NB) cur[t] = table[t * nchunks + c];
  __syncthreads();
  int base = c * CHUNK;
  int lim = base + CHUNK < E ? base + CHUNK : E;
  for (int e = base + t; e < lim; e += 256) {
    int d = dst[e];
    int pos = atomicAdd(&cur[d >> 10], 1);
    inter[pos] = (src[e] << 10) | (d & 1023);
  }
}

// ---- K4: bdeg (blocks < nbk): per-bucket degree histogram -> in-LDS scan
// -> offs + dinv.  + gemm tiles (rest). ----
__global__ __launch_bounds__(256) void bdeg_gemm_kernel(
    const int* __restrict__ inter, const int* __restrict__ bstart,
    int* __restrict__ offs, float* __restrict__ dinv,
    const float* __restrict__ x, const unsigned short* __restrict__ wfh,
    const unsigned short* __restrict__ wfl, unsigned short* __restrict__ h,
    int n, int E, int nbk, int tbase) {
  if ((int)blockIdx.x >= nbk) {
    gemm_tile(x, wfh, wfl, h, n, tbase + (int)blockIdx.x - nbk);
    return;
  }
  __shared__ int dl[1024];
  __shared__ int sh[256];
  int t = threadIdx.x;
  int b = blockIdx.x;
  for (int i = t; i < 1024; i += 256) dl[i] = 0;
  __syncthreads();
  int lo = bstart[b], hi = bstart[b + 1];
  for (int e = lo + t; e < hi; e += 256) atomicAdd(&dl[inter[e] & 1023], 1);
  __syncthreads();
  int c[4];
  int s = 0;
#pragma unroll
  for (int j = 0; j < 4; j++) {
    c[j] = dl[t * 4 + j];
    s += c[j];
  }
  sh[t] = s;
  __syncthreads();
  for (int off = 1; off < 256; off <<= 1) {
    int x2 = sh[t];
    if (t >= off) x2 += sh[t - off];
    __syncthreads();
    sh[t] = x2;
    __syncthreads();
  }
  int run = sh[t] - s + lo;
  int nb0 = b << 10;
#pragma unroll
  for (int j = 0; j < 4; j++) {
    int node = nb0 + t * 4 + j;
    if (node < n) {
      offs[node] = run;
      dinv[node] = rsqrtf((float)c[j] + 1.0f);
    }
    run += c[j];
  }
  if (b == nbk - 1 && t == 255) offs[n] = E;
}

// ---- K5: scat3 (blocks < nbk) + hscale (rest) ----
// scat3: per-bucket CSR fill via LDS cursors (reload offs).
// hscale: h2 = bf16(h_raw * dinv[row]) — dinv/h both complete after K4.
__global__ __launch_bounds__(256) void scat3_hscale_kernel(
    const int* __restrict__ inter, const int* __restrict__ bstart,
    const int* __restrict__ offs, int* __restrict__ csr_src,
    uint4* __restrict__ hw, const float* __restrict__ dinv,
    int n, int nbk) {
  int t = threadIdx.x;
  if ((int)blockIdx.x >= nbk) {
    int gid = ((int)blockIdx.x - nbk) * 256 + t;  // one uint4 = 8 bf16
    int total = n * 16;                           // 16 uint4 per 128-col row
    if (gid >= total) return;
    int row = gid >> 4;
    float d = dinv[row];
    uint4 u = hw[gid];
    auto sc = [&](unsigned int v) -> unsigned int {
      unsigned short lb = bfbits((__bf16)(bflo(v) * d));
      unsigned short hb = bfbits((__bf16)(bfhi(v) * d));
      return (unsigned int)lb | ((unsigned int)hb << 16);
    };
    u.x = sc(u.x); u.y = sc(u.y); u.z = sc(u.z); u.w = sc(u.w);
    hw[gid] = u;
    return;
  }
  __shared__ int curs[1024];
  int b = blockIdx.x;
  int nb0 = b << 10;
  for (int i = t; i < 1024; i += 256) {
    int node = nb0 + i;
    curs[i] = (node < n) ? offs[node] : 0;
  }
  __syncthreads();
  int lo = bstart[b], hi = bstart[b + 1];
  for (int e = lo + t; e < hi; e += 256) {
    int u = inter[e];
    int pos = atomicAdd(&curs[u & 1023], 1);
    csr_src[pos] = u >> 10;
  }
}

// ---- K6: gather (h2 pre-scaled): out[d] = dinv[d]*(sum_e h2[src_e] + h2[d]) + b.
// One node per wave; each 16-lane quarter owns one edge; lane loads uint4.
__global__ __launch_bounds__(256) void gather_kernel(const int* __restrict__ offs,
                                                     const int* __restrict__ csr_src,
                                                     const unsigned short* __restrict__ h,
                                                     const float* __restrict__ dinv,
                                                     const float* __restrict__ b,
                                                     float* __restrict__ out,
                                                     int n, int tail) {
  int wid = threadIdx.x >> 6;
  int lane = threadIdx.x & 63;
  int l15 = lane & 15;
  int q = lane >> 4;  // quarter 0..3
  int node = blockIdx.x * 4 + wid;
  if (node >= n) return;

  int start = offs[node];
  int end = offs[node + 1];

  float ax0 = 0, ay0 = 0, ax1 = 0, ay1 = 0, ax2 = 0, ay2 = 0, ax3 = 0, ay3 = 0;

  int e = start + q;
  for (; e + 12 < end; e += 16) {
    int s0 = csr_src[e];
    int s1 = csr_src[e + 4];
    int s2 = csr_src[e + 8];
    int s3 = csr_src[e + 12];
    uint4 u0 = *(const uint4*)(h + (size_t)s0 * OUT_C + l15 * 8);
    uint4 u1 = *(const uint4*)(h + (size_t)s1 * OUT_C + l15 * 8);
    uint4 u2 = *(const uint4*)(h + (size_t)s2 * OUT_C + l15 * 8);
    uint4 u3 = *(const uint4*)(h + (size_t)s3 * OUT_C + l15 * 8);
    ax0 += (bflo(u0.x) + bflo(u1.x)) + (bflo(u2.x) + bflo(u3.x));
    ay0 += (bfhi(u0.x) + bfhi(u1.x)) + (bfhi(u2.x) + bfhi(u3.x));
    ax1 += (bflo(u0.y) + bflo(u1.y)) + (bflo(u2.y) + bflo(u3.y));
    ay1 += (bfhi(u0.y) + bfhi(u1.y)) + (bfhi(u2.y) + bfhi(u3.y));
    ax2 += (bflo(u0.z) + bflo(u1.z)) + (bflo(u2.z) + bflo(u3.z));
    ay2 += (bfhi(u0.z) + bfhi(u1.z)) + (bfhi(u2.z) + bfhi(u3.z));
    ax3 += (bflo(u0.w) + bflo(u1.w)) + (bflo(u2.w) + bflo(u3.w));
    ay3 += (bfhi(u0.w) + bfhi(u1.w)) + (bfhi(u2.w) + bfhi(u3.w));
  }
  for (; e < end; e += 4) {
    int s0 = csr_src[e];
    uint4 u0 = *(const uint4*)(h + (size_t)s0 * OUT_C + l15 * 8);
    ax0 += bflo(u0.x); ay0 += bfhi(u0.x);
    ax1 += bflo(u0.y); ay1 += bfhi(u0.y);
    ax2 += bflo(u0.z); ay2 += bfhi(u0.z);
    ax3 += bflo(u0.w); ay3 += bfhi(u0.w);
  }

#pragma unroll
  for (int mask = 16; mask <= 32; mask <<= 1) {
    ax0 += __shfl_xor(ax0, mask); ay0 += __shfl_xor(ay0, mask);
    ax1 += __shfl_xor(ax1, mask); ay1 += __shfl_xor(ay1, mask);
    ax2 += __shfl_xor(ax2, mask); ay2 += __shfl_xor(ay2, mask);
    ax3 += __shfl_xor(ax3, mask); ay3 += __shfl_xor(ay3, mask);
  }

  float dd = dinv[node];
  uint4 us = *(const uint4*)(h + (size_t)node * OUT_C + l15 * 8);
  ax0 = (ax0 + bflo(us.x)) * dd; ay0 = (ay0 + bfhi(us.x)) * dd;
  ax1 = (ax1 + bflo(us.y)) * dd; ay1 = (ay1 + bfhi(us.y)) * dd;
  ax2 = (ax2 + bflo(us.z)) * dd; ay2 = (ay2 + bfhi(us.z)) * dd;
  ax3 = (ax3 + bflo(us.w)) * dd; ay3 = (ay3 + bfhi(us.w)) * dd;

  if (q == 0) {
    float4 b0 = *(const float4*)(b + l15 * 8);
    float4 b1 = *(const float4*)(b + l15 * 8 + 4);
    float4 o0 = make_float4(ax0 + b0.x, ay0 + b0.y, ax1 + b0.z, ay1 + b0.w);
    float4 o1 = make_float4(ax2 + b1.x, ay2 + b1.y, ax3 + b1.z, ay3 + b1.w);
    float* op = out + (size_t)node * OUT_C + l15 * 8;
    *(float4*)op = o0;
    *(float4*)(op + 4) = o1;
  }

  if (node == 0 && lane == 0) {
    for (int t = 0; t < tail; t++) out[(size_t)n * OUT_C + t] = 0.0f;
  }
}

extern "C" void kernel_launch(void* const* d_in, const int* in_sizes, int n_in,
                              void* d_out, int out_size, void* d_ws, size_t ws_size,
                              hipStream_t stream) {
  const float* x = (const float*)d_in[0];
  const int* ei = (const int*)d_in[1];
  const float* W = (const float*)d_in[2];
  const float* b = (const float*)d_in[3];

  const int n = in_sizes[0] / IN_C;
  const int E = in_sizes[1] / 2;
  const int* src = ei;
  const int* dst = ei + E;
  float* out = (float*)d_out;

  const int nchunks = cdiv(E, CHUNK);
  const int nbk = cdiv(n, 1024);
  const int ntiles = cdiv(n, 128);
  // tile split across K2/K3/K4
  int t2 = ntiles < 255 ? ntiles : 255;
  int rem = ntiles - t2;
  int t3 = rem < 400 ? rem : 400;
  int t4 = rem - t3;
  const int nhs = cdiv(n * 16, 256);  // hscale blocks

  size_t p = 0;
  auto alloc = [&](size_t bytes) { size_t o = p; p += (bytes + 255) & ~(size_t)255; return o; };
  char* ws = (char*)d_ws;
  float*          dinv   = (float*)(ws + alloc((size_t)n * 4));
  int*            offs   = (int*)(ws + alloc(((size_t)n + 1) * 4));
  int*            csrsrc = (int*)(ws + alloc((size_t)E * 4));
  int*            bstart = (int*)(ws + alloc((NB + 1) * 4));
  unsigned short* wfh    = (unsigned short*)(ws + alloc((size_t)IN_C * OUT_C * 2));
  unsigned short* wfl    = (unsigned short*)(ws + alloc((size_t)IN_C * OUT_C * 2));
  unsigned short* h      = (unsigned short*)(ws + alloc((size_t)n * OUT_C * 2));
  int*            inter  = (int*)(ws + alloc((size_t)E * 4));
  int*            table  = (int*)(ws + alloc((size_t)NB * nchunks * 4));

  hist_kernel<<<nchunks + 256, 256, 0, stream>>>(dst, table, W, wfh, wfl, nchunks, E);
  tscan_gemm_kernel<<<1 + t2, 256, 0, stream>>>(table, bstart, x, wfh, wfl, h,
                                                nchunks, E, n, 0);
  scat2_gemm_kernel<<<nchunks + t3, 256, 0, stream>>>(src, dst, table, inter,
                                                      x, wfh, wfl, h, nchunks, E, n, t2);
  bdeg_gemm_kernel<<<nbk + t4, 256, 0, stream>>>(inter, bstart, offs, dinv,
                                                 x, wfh, wfl, h, n, E, nbk, t2 + t3);
  scat3_hscale_kernel<<<nbk + nhs, 256, 0, stream>>>(inter, bstart, offs, csrsrc,
                                                     (uint4*)h, dinv, n, nbk);
  int tail = out_size - n * OUT_C;
  gather_kernel<<<cdiv(n, 4), 256, 0, stream>>>(offs, csrsrc, h, dinv, b, out, n, tail);
}

// Round 18
// 243.166 us; speedup vs baseline: 1.1154x; 1.1154x over previous
//
#include <hip/hip_runtime.h>

#define IN_C 512
#define OUT_C 128
#define NB 128          // dst buckets (dst >> 10)
#define CHUNK 8192      // edges per chunk (196 blocks @ E=1.6M) — measured-good

typedef float f32x4 __attribute__((ext_vector_type(4)));
typedef __bf16 bf16x8 __attribute__((ext_vector_type(8)));

static inline int cdiv(int a, int b) { return (a + b - 1) / b; }

__device__ __forceinline__ unsigned short bfbits(__bf16 h) {
  return __builtin_bit_cast(unsigned short, h);
}
__device__ __forceinline__ float bflo(unsigned int u) {
  return __builtin_bit_cast(float, u << 16);
}
__device__ __forceinline__ float bfhi(unsigned int u) {
  return __builtin_bit_cast(float, u & 0xffff0000u);
}

// ---- K1: per-chunk bucket histogram (+ wsplit on extra blocks) ----
__global__ __launch_bounds__(256) void hist_kernel(const int* __restrict__ dst,
                                                   int* __restrict__ table,
                                                   const float* __restrict__ W,
                                                   unsigned short* __restrict__ wfh,
                                                   unsigned short* __restrict__ wfl,
                                                   int nchunks, int E) {
  int c = blockIdx.x;
  int t = threadIdx.x;
  if (c >= nchunks) {
    int i = (c - nchunks) * 256 + t;
    if (i < IN_C * OUT_C) {
      int k = i >> 7;
      int col = i & 127;
      float w = W[i];
      __bf16 hb = (__bf16)w;
      __bf16 lb = (__bf16)(w - (float)hb);
      int ks = k >> 5;
      int lg = (k & 31) >> 3;
      int j = k & 7;
      int cb = col >> 4;
      int lane = lg * 16 + (col & 15);
      size_t idx = ((size_t)(ks * 8 + cb) * 64 + lane) * 8 + j;
      wfh[idx] = bfbits(hb);
      wfl[idx] = bfbits(lb);
    }
    return;
  }
  __shared__ int hcnt[NB];
  if (t < NB) hcnt[t] = 0;
  __syncthreads();
  int base = c * CHUNK;
  int lim = base + CHUNK < E ? base + CHUNK : E;
  for (int e = base + t; e < lim; e += 256) {
    atomicAdd(&hcnt[dst[e] >> 10], 1);
  }
  __syncthreads();
  if (t < NB) table[t * nchunks + c] = hcnt[t];
}

// ---- GEMM tile (device fn): h_raw[row][:] = bf16((x @ W)[row][:]) for one
// 128-row tile. 2-term split-bf16 MFMA, BK=32 double-buffered LDS via
// global_load_lds (16B slots, XOR-swizzled source). Body measured-good; frozen.
// NOTE: no dinv scale here (dinv not ready while tiles overlap the sort chain);
// hscale_kernel applies it afterwards.
__device__ __forceinline__ void gemm_tile(
    const float* __restrict__ x, const unsigned short* __restrict__ wfh,
    const unsigned short* __restrict__ wfl, unsigned short* __restrict__ h,
    int n, int tile) {
  __shared__ float xs[2][4096];  // 2 x 16KB: [128 rows][32 k] swizzled

  const int tid = threadIdx.x;
  const int wv = tid >> 6;
  const int lane = tid & 63;
  const int l15 = lane & 15;
  const int lg = lane >> 4;
  const int wr = wv >> 1;
  const int wc = wv & 1;
  const int row0 = tile * 128;

  const float* gsrc[4];
#pragma unroll
  for (int i = 0; i < 4; i++) {
    int pslot = i * 256 + tid;
    int row = pslot >> 3;
    int q = pslot & 7;
    int s = q ^ (row & 7);
    int grow = row0 + row;
    if (grow > n - 1) grow = n - 1;
    gsrc[i] = x + (size_t)grow * IN_C + s * 4;
  }

  const unsigned short* bph = wfh + ((size_t)(wc * 4) * 64 + lane) * 8;
  const unsigned short* bpl = wfl + ((size_t)(wc * 4) * 64 + lane) * 8;

  f32x4 acc[4][4];
#pragma unroll
  for (int i = 0; i < 4; i++)
#pragma unroll
    for (int j = 0; j < 4; j++) acc[i][j] = (f32x4)0.0f;

#pragma unroll
  for (int i = 0; i < 4; i++) {
    char* lp = (char*)&xs[0][0] + i * 4096 + wv * 1024;
    __builtin_amdgcn_global_load_lds(
        (const __attribute__((address_space(1))) void*)gsrc[i],
        (__attribute__((address_space(3))) void*)lp, 16, 0, 0);
    gsrc[i] += 32;
  }
  __syncthreads();

  int cur = 0;
  for (int ks = 0; ks < 16; ks++) {
    if (ks < 15) {
#pragma unroll
      for (int i = 0; i < 4; i++) {
        char* lp = (char*)&xs[cur ^ 1][0] + i * 4096 + wv * 1024;
        __builtin_amdgcn_global_load_lds(
            (const __attribute__((address_space(1))) void*)gsrc[i],
            (__attribute__((address_space(3))) void*)lp, 16, 0, 0);
        gsrc[i] += 32;
      }
    }
    bf16x8 bh[4], bl[4];
#pragma unroll
    for (int nt = 0; nt < 4; nt++) {
      bh[nt] = __builtin_bit_cast(bf16x8, *(const uint4*)(bph + (size_t)ks * 4096 + nt * 512));
      bl[nt] = __builtin_bit_cast(bf16x8, *(const uint4*)(bpl + (size_t)ks * 4096 + nt * 512));
    }
    const float* bp = &xs[cur][0];
    bf16x8 ah[4];
#pragma unroll
    for (int rt = 0; rt < 4; rt++) {
      int row = wr * 64 + rt * 16 + l15;
      int r7 = row & 7;
      int s0 = (lg * 2) ^ r7;
      int s1 = (lg * 2 + 1) ^ r7;
      float4 f0 = *(const float4*)(bp + row * 32 + s0 * 4);
      float4 f1 = *(const float4*)(bp + row * 32 + s1 * 4);
      float f[8] = {f0.x, f0.y, f0.z, f0.w, f1.x, f1.y, f1.z, f1.w};
      bf16x8 hh;
#pragma unroll
      for (int j = 0; j < 8; j++) hh[j] = (__bf16)f[j];
      ah[rt] = hh;
    }
#pragma unroll
    for (int rt = 0; rt < 4; rt++)
#pragma unroll
      for (int nt = 0; nt < 4; nt++) {
        acc[rt][nt] = __builtin_amdgcn_mfma_f32_16x16x32_bf16(ah[rt], bh[nt], acc[rt][nt], 0, 0, 0);
        acc[rt][nt] = __builtin_amdgcn_mfma_f32_16x16x32_bf16(ah[rt], bl[nt], acc[rt][nt], 0, 0, 0);
      }
    __syncthreads();
    cur ^= 1;
  }

#pragma unroll
  for (int rt = 0; rt < 4; rt++) {
    int rowbase = row0 + wr * 64 + rt * 16 + lg * 4;
#pragma unroll
    for (int r = 0; r < 4; r++) {
      int row = rowbase + r;
      if (row < n) {
#pragma unroll
        for (int nt = 0; nt < 4; nt++) {
          int col = wc * 64 + nt * 16 + l15;
          h[(size_t)row * OUT_C + col] = bfbits((__bf16)acc[rt][nt][r]);
        }
      }
    }
  }
}

// ---- K2: tscan (block 0) + gemm tiles (blocks 1..) ----
__global__ __launch_bounds__(256) void tscan_gemm_kernel(
    int* __restrict__ table, int* __restrict__ bstart,
    const float* __restrict__ x, const unsigned short* __restrict__ wfh,
    const unsigned short* __restrict__ wfl, unsigned short* __restrict__ h,
    int nchunks, int E, int n, int tbase) {
  if (blockIdx.x != 0) {
    gemm_tile(x, wfh, wfl, h, n, tbase + (int)blockIdx.x - 1);
    return;
  }
  __shared__ int sh[256];
  int t = threadIdx.x;
  int total = NB * nchunks;
  int S = (total + 255) / 256;
  int lo = t * S;
  int hi = lo + S; if (hi > total) hi = total;
  int s = 0;
  int i = lo;
  for (; i + 4 <= hi; i += 4)
    s += table[i] + table[i + 1] + table[i + 2] + table[i + 3];
  for (; i < hi; i++) s += table[i];
  sh[t] = s;
  __syncthreads();
  for (int off = 1; off < 256; off <<= 1) {
    int x2 = sh[t];
    if (t >= off) x2 += sh[t - off];
    __syncthreads();
    sh[t] = x2;
    __syncthreads();
  }
  int run = sh[t] - s;
  for (i = lo; i < hi; i++) {
    int v = table[i];
    table[i] = run;
    run += v;
  }
  __syncthreads();
  for (int b = t; b < NB; b += 256) bstart[b] = table[b * nchunks];
  if (t == 0) bstart[NB] = E;
}

// ---- K3: scat2 (blocks < nchunks) + gemm tiles (rest) ----
// scatter edges into bucket-major packed inter[]: (src<<10) | (dst&1023)
__global__ __launch_bounds__(256) void scat2_gemm_kernel(
    const int* __restrict__ src, const int* __restrict__ dst,
    const int* __restrict__ table, int* __restrict__ inter,
    const float* __restrict__ x, const unsigned short* __restrict__ wfh,
    const unsigned short* __restrict__ wfl, unsigned short* __restrict__ h,
    int nchunks, int E, int n, int tbase) {
  if ((int)blockIdx.x >= nchunks) {
    gemm_tile(x, wfh, wfl, h, n, tbase + (int)blockIdx.x - nchunks);
    return;
  }
  __shared__ int cur[NB];
  int t = threadIdx.x;
  int c = blockIdx.x;
  if (t < NB) cur[t] = table[t * nchunks + c];
  __syncthreads();
  int base = c * CHUNK;
  int lim = base + CHUNK < E ? base + CHUNK : E;
  for (int e = base + t; e < lim; e += 256) {
    int d = dst[e];
    int pos = atomicAdd(&cur[d >> 10], 1);
    inter[pos] = (src[e] << 10) | (d & 1023);
  }
}

// ---- K4: bucket_csr (blocks < nbk) + gemm tiles (rest) ----
// per-bucket fused: degree histogram -> in-LDS scan -> offs+dinv -> CSR scatter.
__global__ __launch_bounds__(256) void bucket_gemm_kernel(
    const int* __restrict__ inter, const int* __restrict__ bstart,
    int* __restrict__ offs, float* __restrict__ dinv, int* __restrict__ csr_src,
    const float* __restrict__ x, const unsigned short* __restrict__ wfh,
    const unsigned short* __restrict__ wfl, unsigned short* __restrict__ h,
    int n, int E, int nbk, int tbase) {
  if ((int)blockIdx.x >= nbk) {
    gemm_tile(x, wfh, wfl, h, n, tbase + (int)blockIdx.x - nbk);
    return;
  }
  __shared__ int dl[1024];
  __shared__ int curs[1024];
  __shared__ int sh[256];
  int t = threadIdx.x;
  int b = blockIdx.x;
  for (int i = t; i < 1024; i += 256) dl[i] = 0;
  __syncthreads();
  int lo = bstart[b], hi = bstart[b + 1];
  for (int e = lo + t; e < hi; e += 256) atomicAdd(&dl[inter[e] & 1023], 1);
  __syncthreads();
  int c[4];
  int s = 0;
#pragma unroll
  for (int j = 0; j < 4; j++) {
    c[j] = dl[t * 4 + j];
    s += c[j];
  }
  sh[t] = s;
  __syncthreads();
  for (int off = 1; off < 256; off <<= 1) {
    int x2 = sh[t];
    if (t >= off) x2 += sh[t - off];
    __syncthreads();
    sh[t] = x2;
    __syncthreads();
  }
  int run = sh[t] - s + lo;
  int nb0 = b << 10;
#pragma unroll
  for (int j = 0; j < 4; j++) {
    int node = nb0 + t * 4 + j;
    if (node < n) {
      offs[node] = run;
      dinv[node] = rsqrtf((float)c[j] + 1.0f);
    }
    curs[t * 4 + j] = run;
    run += c[j];
  }
  if (b == nbk - 1 && t == 255) offs[n] = E;
  __syncthreads();
  for (int e = lo + t; e < hi; e += 256) {
    int u = inter[e];
    int pos = atomicAdd(&curs[u & 1023], 1);
    csr_src[pos] = u >> 10;
  }
}

// ---- K5: h2 = bf16(h_raw * dinv[row]) ----
__global__ __launch_bounds__(256) void hscale_kernel(uint4* __restrict__ hw,
                                                     const float* __restrict__ dinv,
                                                     int n) {
  int gid = blockIdx.x * 256 + threadIdx.x;  // one uint4 = 8 bf16
  int total = n * 16;                        // 16 uint4 per 128-col row
  if (gid >= total) return;
  int row = gid >> 4;
  float d = dinv[row];
  uint4 u = hw[gid];
  auto sc = [&](unsigned int v) -> unsigned int {
    unsigned short lb = bfbits((__bf16)(bflo(v) * d));
    unsigned short hb = bfbits((__bf16)(bfhi(v) * d));
    return (unsigned int)lb | ((unsigned int)hb << 16);
  };
  u.x = sc(u.x); u.y = sc(u.y); u.z = sc(u.z); u.w = sc(u.w);
  hw[gid] = u;
}

// ---- K6: gather (h2 pre-scaled): out[d] = dinv[d]*(sum_e h2[src_e] + h2[d]) + b.
// One node per wave; each 16-lane quarter owns one edge; lane loads uint4.
__global__ __launch_bounds__(256) void gather_kernel(const int* __restrict__ offs,
                                                     const int* __restrict__ csr_src,
                                                     const unsigned short* __restrict__ h,
                                                     const float* __restrict__ dinv,
                                                     const float* __restrict__ b,
                                                     float* __restrict__ out,
                                                     int n, int tail) {
  int wid = threadIdx.x >> 6;
  int lane = threadIdx.x & 63;
  int l15 = lane & 15;
  int q = lane >> 4;  // quarter 0..3
  int node = blockIdx.x * 4 + wid;
  if (node >= n) return;

  int start = offs[node];
  int end = offs[node + 1];

  float ax0 = 0, ay0 = 0, ax1 = 0, ay1 = 0, ax2 = 0, ay2 = 0, ax3 = 0, ay3 = 0;

  int e = start + q;
  for (; e + 12 < end; e += 16) {
    int s0 = csr_src[e];
    int s1 = csr_src[e + 4];
    int s2 = csr_src[e + 8];
    int s3 = csr_src[e + 12];
    uint4 u0 = *(const uint4*)(h + (size_t)s0 * OUT_C + l15 * 8);
    uint4 u1 = *(const uint4*)(h + (size_t)s1 * OUT_C + l15 * 8);
    uint4 u2 = *(const uint4*)(h + (size_t)s2 * OUT_C + l15 * 8);
    uint4 u3 = *(const uint4*)(h + (size_t)s3 * OUT_C + l15 * 8);
    ax0 += (bflo(u0.x) + bflo(u1.x)) + (bflo(u2.x) + bflo(u3.x));
    ay0 += (bfhi(u0.x) + bfhi(u1.x)) + (bfhi(u2.x) + bfhi(u3.x));
    ax1 += (bflo(u0.y) + bflo(u1.y)) + (bflo(u2.y) + bflo(u3.y));
    ay1 += (bfhi(u0.y) + bfhi(u1.y)) + (bfhi(u2.y) + bfhi(u3.y));
    ax2 += (bflo(u0.z) + bflo(u1.z)) + (bflo(u2.z) + bflo(u3.z));
    ay2 += (bfhi(u0.z) + bfhi(u1.z)) + (bfhi(u2.z) + bfhi(u3.z));
    ax3 += (bflo(u0.w) + bflo(u1.w)) + (bflo(u2.w) + bflo(u3.w));
    ay3 += (bfhi(u0.w) + bfhi(u1.w)) + (bfhi(u2.w) + bfhi(u3.w));
  }
  for (; e < end; e += 4) {
    int s0 = csr_src[e];
    uint4 u0 = *(const uint4*)(h + (size_t)s0 * OUT_C + l15 * 8);
    ax0 += bflo(u0.x); ay0 += bfhi(u0.x);
    ax1 += bflo(u0.y); ay1 += bfhi(u0.y);
    ax2 += bflo(u0.z); ay2 += bfhi(u0.z);
    ax3 += bflo(u0.w); ay3 += bfhi(u0.w);
  }

#pragma unroll
  for (int mask = 16; mask <= 32; mask <<= 1) {
    ax0 += __shfl_xor(ax0, mask); ay0 += __shfl_xor(ay0, mask);
    ax1 += __shfl_xor(ax1, mask); ay1 += __shfl_xor(ay1, mask);
    ax2 += __shfl_xor(ax2, mask); ay2 += __shfl_xor(ay2, mask);
    ax3 += __shfl_xor(ax3, mask); ay3 += __shfl_xor(ay3, mask);
  }

  float dd = dinv[node];
  uint4 us = *(const uint4*)(h + (size_t)node * OUT_C + l15 * 8);
  ax0 = (ax0 + bflo(us.x)) * dd; ay0 = (ay0 + bfhi(us.x)) * dd;
  ax1 = (ax1 + bflo(us.y)) * dd; ay1 = (ay1 + bfhi(us.y)) * dd;
  ax2 = (ax2 + bflo(us.z)) * dd; ay2 = (ay2 + bfhi(us.z)) * dd;
  ax3 = (ax3 + bflo(us.w)) * dd; ay3 = (ay3 + bfhi(us.w)) * dd;

  if (q == 0) {
    float4 b0 = *(const float4*)(b + l15 * 8);
    float4 b1 = *(const float4*)(b + l15 * 8 + 4);
    float4 o0 = make_float4(ax0 + b0.x, ay0 + b0.y, ax1 + b0.z, ay1 + b0.w);
    float4 o1 = make_float4(ax2 + b1.x, ay2 + b1.y, ax3 + b1.z, ay3 + b1.w);
    float* op = out + (size_t)node * OUT_C + l15 * 8;
    *(float4*)op = o0;
    *(float4*)(op + 4) = o1;
  }

  if (node == 0 && lane == 0) {
    for (int t = 0; t < tail; t++) out[(size_t)n * OUT_C + t] = 0.0f;
  }
}

extern "C" void kernel_launch(void* const* d_in, const int* in_sizes, int n_in,
                              void* d_out, int out_size, void* d_ws, size_t ws_size,
                              hipStream_t stream) {
  const float* x = (const float*)d_in[0];
  const int* ei = (const int*)d_in[1];
  const float* W = (const float*)d_in[2];
  const float* b = (const float*)d_in[3];

  const int n = in_sizes[0] / IN_C;
  const int E = in_sizes[1] / 2;
  const int* src = ei;
  const int* dst = ei + E;
  float* out = (float*)d_out;

  const int nchunks = cdiv(E, CHUNK);
  const int nbk = cdiv(n, 1024);
  const int ntiles = cdiv(n, 128);
  // tile split across K2/K3/K4, sized to overlap each phase's sort work
  int t2 = ntiles < 128 ? ntiles : 128;
  int rem = ntiles - t2;
  int t3 = rem < 416 ? rem : 416;
  int t4 = rem - t3;

  size_t p = 0;
  auto alloc = [&](size_t bytes) { size_t o = p; p += (bytes + 255) & ~(size_t)255; return o; };
  char* ws = (char*)d_ws;
  float*          dinv   = (float*)(ws + alloc((size_t)n * 4));
  int*            offs   = (int*)(ws + alloc(((size_t)n + 1) * 4));
  int*            csrsrc = (int*)(ws + alloc((size_t)E * 4));
  int*            bstart = (int*)(ws + alloc((NB + 1) * 4));
  unsigned short* wfh    = (unsigned short*)(ws + alloc((size_t)IN_C * OUT_C * 2));
  unsigned short* wfl    = (unsigned short*)(ws + alloc((size_t)IN_C * OUT_C * 2));
  unsigned short* h      = (unsigned short*)(ws + alloc((size_t)n * OUT_C * 2));  // own slab: live concurrently with inter/table
  int*            inter  = (int*)(ws + alloc((size_t)E * 4));
  int*            table  = (int*)(ws + alloc((size_t)NB * nchunks * 4));

  hist_kernel<<<nchunks + 256, 256, 0, stream>>>(dst, table, W, wfh, wfl, nchunks, E);
  tscan_gemm_kernel<<<1 + t2, 256, 0, stream>>>(table, bstart, x, wfh, wfl, h,
                                                nchunks, E, n, 0);
  scat2_gemm_kernel<<<nchunks + t3, 256, 0, stream>>>(src, dst, table, inter,
                                                      x, wfh, wfl, h, nchunks, E, n, t2);
  bucket_gemm_kernel<<<nbk + t4, 256, 0, stream>>>(inter, bstart, offs, dinv, csrsrc,
                                                   x, wfh, wfl, h, n, E, nbk, t2 + t3);
  hscale_kernel<<<cdiv(n * 16, 256), 256, 0, stream>>>((uint4*)h, dinv, n);
  int tail = out_size - n * OUT_C;
  gather_kernel<<<cdiv(n, 4), 256, 0, stream>>>(offs, csrsrc, h, dinv, b, out, n, tail);
}